// Round 14
// baseline (261.987 us; speedup 1.0000x reference)
//
#include <hip/hip_runtime.h>

#define NB 16
#define DMODEL 4096
#define NH 32
#define NKV 8
#define HD 128
#define SEQ 4096
#define PASTN 4095
#define EQKV 6144           // 4096 q + 1024 k + 1024 v rows
#define NCHUNK 16
#define CHUNKS 256          // rows per chunk-block (SEQ/NCHUNK)
#define PSTRIDE 136         // partials stride (16B aligned)
#define SCALE 0.08838834764831845f  // 1/sqrt(128)

typedef float v4f __attribute__((ext_vector_type(4)));

// ---------------- Kernel 1: QKV projection, double-buffered staging --------
__global__ __launch_bounds__(256) void qkv_proj(
    const float* __restrict__ hs, const float* __restrict__ Wq,
    const float* __restrict__ Wk, const float* __restrict__ Wv,
    float* __restrict__ raw /* [B][6144] */) {
  __shared__ __align__(16) float ld[2][16][256];   // 32 KB
  __shared__ __align__(16) float red[4][32][33];   // 16.9 KB
  const int tid = threadIdx.x, wid = tid >> 6, lane = tid & 63;
  const int e0 = blockIdx.x * 8 + wid * 2;
  const int fo = lane * 4;

  const float* wrow[2];
#pragma unroll
  for (int r = 0; r < 2; ++r) {
    int e = e0 + r;
    wrow[r] = (e < 4096) ? (Wq + (size_t)e * DMODEL)
            : (e < 5120) ? (Wk + (size_t)(e - 4096) * DMODEL)
                         : (Wv + (size_t)(e - 5120) * DMODEL);
  }

  float acc[2][16];
#pragma unroll
  for (int r = 0; r < 2; ++r)
#pragma unroll
    for (int b = 0; b < 16; ++b) acc[r][b] = 0.f;

  v4f st[4];
#pragma unroll
  for (int i = 0; i < 4; ++i)
    st[i] = *(const v4f*)(hs + (size_t)(i * 4 + wid) * DMODEL + fo);
#pragma unroll
  for (int i = 0; i < 4; ++i)
    *(v4f*)(&ld[0][i * 4 + wid][fo]) = st[i];
  v4f w4[2];
#pragma unroll
  for (int r = 0; r < 2; ++r) w4[r] = *(const v4f*)(wrow[r] + fo);
  __syncthreads();

  for (int c = 0; c < 16; ++c) {
    const int k1 = (c + 1) * 256;
    v4f w4n[2];
    if (c < 15) {
#pragma unroll
      for (int i = 0; i < 4; ++i)
        st[i] = *(const v4f*)(hs + (size_t)(i * 4 + wid) * DMODEL + k1 + fo);
#pragma unroll
      for (int r = 0; r < 2; ++r) w4n[r] = *(const v4f*)(wrow[r] + k1 + fo);
    }
    const float* lb = &ld[c & 1][0][0];
#pragma unroll
    for (int b = 0; b < 16; ++b) {
      v4f h4 = *(const v4f*)(lb + b * 256 + fo);
#pragma unroll
      for (int r = 0; r < 2; ++r) {
        v4f t = w4[r] * h4;
        acc[r][b] += t[0] + t[1] + t[2] + t[3];
      }
    }
    if (c < 15) {
#pragma unroll
      for (int i = 0; i < 4; ++i)
        *(v4f*)(&ld[(c + 1) & 1][i * 4 + wid][fo]) = st[i];
      w4[0] = w4n[0];
      w4[1] = w4n[1];
    }
    __syncthreads();
  }

#pragma unroll
  for (int r = 0; r < 2; ++r)
#pragma unroll
    for (int b = 0; b < 16; ++b) acc[r][b] += __shfl_xor(acc[r][b], 32);

  if (lane < 32) {
#pragma unroll
    for (int r = 0; r < 2; ++r)
#pragma unroll
      for (int b = 0; b < 16; ++b)
        red[wid][lane][r * 16 + b] = acc[r][b];
  }
  __syncthreads();
  if (lane < 32) {
    float s = 0.f;
#pragma unroll
    for (int t2 = 0; t2 < 32; ++t2) s += red[wid][t2][lane];
    const int r = lane >> 4, bb = lane & 15;
    raw[(size_t)bb * EQKV + e0 + r] = s;
  }
}

// ---------------- Kernel 2: RoPE + scatter (R12 form) ---------------------
__device__ __forceinline__ float rope_val(const float* src, int d, float pos) {
  int i = d & 63;
  float inv_freq = powf(10000.f, -(float)(2 * i) * (1.f / 128.f));
  float ang = pos * inv_freq;
  float s, c;
  sincosf(ang, &s, &c);
  float x = src[d];
  float rot = (d < 64) ? -src[d + 64] : src[d - 64];
  return x * c + rot * s;
}

__global__ void rope_scatter(const float* __restrict__ raw,
                             const void* __restrict__ pos_ids,
                             float* __restrict__ qout,
                             float* __restrict__ kc, float* __restrict__ vc) {
  const int b = blockIdx.y, j = blockIdx.x, d = threadIdx.x;  // 128 threads
  const int* pi = (const int*)pos_ids;
  long long pos = (pi[1] == 0 && pi[0] != 0) ? ((const long long*)pos_ids)[b]
                                             : (long long)pi[b];
  const float fpos = (float)pos;
  if (j < 32) {
    const float* src = raw + (size_t)b * EQKV + j * HD;
    qout[(size_t)b * (NH * HD) + j * HD + d] = rope_val(src, d, fpos);
  } else if (j < 40) {
    int kvh = j - 32;
    const float* src = raw + (size_t)b * EQKV + 4096 + kvh * HD;
    kc[(((size_t)b * NKV + kvh) * SEQ + PASTN) * HD + d] = rope_val(src, d, fpos);
  } else {
    int kvh = j - 40;
    vc[(((size_t)b * NKV + kvh) * SEQ + PASTN) * HD + d] =
        raw[(size_t)b * EQKV + 5120 + kvh * HD + d];
  }
}

// ---------------- Kernel 3: phase-split flash-decode, 4-row steps ----------
// grid (16,8,16) = 2048 blocks; 4 waves/block; wave owns 64 rows.
// lane = r*16+g: row-quad member r, dim-group g holding dims [4g,4g+4) and
// [64+4g,+4). 4-row/2KB steps; 4-level shuffle reduce (17 DS ops per 4 rows
// vs 42 in the 2-row version). True-max exact softmax, NT streams.
__global__ __launch_bounds__(256, 4) void attn_decode(
    const float* __restrict__ pastK, const float* __restrict__ pastV,
    const float* __restrict__ qv, const float* __restrict__ mask,
    float* __restrict__ kc, float* __restrict__ vc,
    float* __restrict__ part /* [B][32][NCHUNK][PSTRIDE] */) {
  __shared__ __align__(16) float sm[4][4][132];  // [wave][head][m,l,pad,ctx128]

  const int chunk = blockIdx.x, kv = blockIdx.y, b = blockIdx.z;
  const int tid = threadIdx.x, wid = tid >> 6, lane = tid & 63;
  const int r = lane >> 4, g = lane & 15;
  const int o0 = g * 4, o1 = 64 + g * 4;   // contiguous-quarter offsets

  v4f qa[4], qb[4];
  const float* qbp = qv + (size_t)b * (NH * HD) + kv * 4 * HD;
#pragma unroll
  for (int h = 0; h < 4; ++h) {
    qa[h] = *(const v4f*)(qbp + h * HD + o0);
    qb[h] = *(const v4f*)(qbp + h * HD + o1);
  }

  const size_t prow = ((size_t)b * NKV + kv) * PASTN;
  const size_t crow = ((size_t)b * NKV + kv) * SEQ;
  const int base = chunk * CHUNKS + wid * 64;
  const float* mrow = mask + (size_t)b * SEQ;

  // lane r*16+g holds mask[base + 4g + r]; step t's value for this lane's
  // row (4t+r) lives at source lane (lane&48)|t.
  const float mreg = mrow[base + 4 * g + r];

  // keep[h]: score of row (4g + r) for head h (filled in phase 1)
  float keep[4];

  // =================== Phase 1: K stream + scores ===================
  {
    v4f ka[4], kb[4];
#pragma unroll
    for (int i = 0; i < 4; ++i) {
      const int s = base + 4 * i + r;
      const float* kp = (s < PASTN) ? pastK + (prow + s) * HD
                                    : kc + (crow + s) * HD;
      ka[i] = __builtin_nontemporal_load((const v4f*)(kp + o0));
      kb[i] = __builtin_nontemporal_load((const v4f*)(kp + o1));
    }

#pragma unroll 4
    for (int t = 0; t < 16; ++t) {
      const int s = base + 4 * t + r;
      const v4f kca = ka[t & 3], kcb = kb[t & 3];
      if (t < 12) {  // prefetch quad t+4
        const int s2 = s + 16;
        const float* kp = (s2 < PASTN) ? pastK + (prow + s2) * HD
                                       : kc + (crow + s2) * HD;
        ka[t & 3] = __builtin_nontemporal_load((const v4f*)(kp + o0));
        kb[t & 3] = __builtin_nontemporal_load((const v4f*)(kp + o1));
      }
      if (s < PASTN) {
        float* kd = kc + (crow + s) * HD;
        __builtin_nontemporal_store(kca, (v4f*)(kd + o0));
        __builtin_nontemporal_store(kcb, (v4f*)(kd + o1));
      }

      const float mval = __shfl(mreg, (lane & 48) | t);

      float d4[4];
#pragma unroll
      for (int h = 0; h < 4; ++h) {
        v4f tv = qa[h] * kca + qb[h] * kcb;
        d4[h] = tv[0] + tv[1] + tv[2] + tv[3];
      }
#pragma unroll
      for (int off = 1; off <= 8; off <<= 1)
#pragma unroll
        for (int h = 0; h < 4; ++h) d4[h] += __shfl_xor(d4[h], off);

#pragma unroll
      for (int h = 0; h < 4; ++h) {
        float sc = d4[h] * SCALE + mval;
        if (g == t) keep[h] = sc;   // row 4t+r kept by lane r*16+t
      }
    }
  }

  // =================== Phase 2: true max, V stream ===================
  float m[4], l[4];
  v4f ca[4], cb[4];
#pragma unroll
  for (int h = 0; h < 4; ++h) {
    float mm = keep[h];
#pragma unroll
    for (int off = 1; off <= 32; off <<= 1)
      mm = fmaxf(mm, __shfl_xor(mm, off));
    m[h] = mm;                        // true max over all 64 rows
    l[h] = 0.f;
    ca[h] = (v4f){0.f, 0.f, 0.f, 0.f};
    cb[h] = (v4f){0.f, 0.f, 0.f, 0.f};
  }

  {
    v4f va[4], vb[4];
#pragma unroll
    for (int i = 0; i < 4; ++i) {
      const int s = base + 4 * i + r;
      const float* vp = (s < PASTN) ? pastV + (prow + s) * HD
                                    : vc + (crow + s) * HD;
      va[i] = __builtin_nontemporal_load((const v4f*)(vp + o0));
      vb[i] = __builtin_nontemporal_load((const v4f*)(vp + o1));
    }

#pragma unroll 4
    for (int t = 0; t < 16; ++t) {
      const int s = base + 4 * t + r;
      const v4f vca = va[t & 3], vcb = vb[t & 3];
      if (t < 12) {
        const int s2 = s + 16;
        const float* vp = (s2 < PASTN) ? pastV + (prow + s2) * HD
                                       : vc + (crow + s2) * HD;
        va[t & 3] = __builtin_nontemporal_load((const v4f*)(vp + o0));
        vb[t & 3] = __builtin_nontemporal_load((const v4f*)(vp + o1));
      }
      if (s < PASTN) {
        float* vd = vc + (crow + s) * HD;
        __builtin_nontemporal_store(vca, (v4f*)(vd + o0));
        __builtin_nontemporal_store(vcb, (v4f*)(vd + o1));
      }

#pragma unroll
      for (int h = 0; h < 4; ++h) {
        float p = __expf(__shfl(keep[h], (lane & 48) | t) - m[h]);
        l[h] += p;
        ca[h] += p * vca;
        cb[h] += p * vcb;
      }
    }
  }

  // reduce l and ctx over the 4 row-groups (lane bits 4,5)
#pragma unroll
  for (int h = 0; h < 4; ++h) {
    l[h] += __shfl_xor(l[h], 16);
    l[h] += __shfl_xor(l[h], 32);
#pragma unroll
    for (int j = 0; j < 4; ++j) {
      ca[h][j] += __shfl_xor(ca[h][j], 16);
      ca[h][j] += __shfl_xor(ca[h][j], 32);
      cb[h][j] += __shfl_xor(cb[h][j], 16);
      cb[h][j] += __shfl_xor(cb[h][j], 32);
    }
  }

  if (r == 0) {
#pragma unroll
    for (int h = 0; h < 4; ++h) {
      if (g == 0) { sm[wid][h][0] = m[h]; sm[wid][h][1] = l[h]; }
      *(v4f*)(&sm[wid][h][4 + o0]) = ca[h];
      *(v4f*)(&sm[wid][h][4 + o1]) = cb[h];
    }
  }
  __syncthreads();

  // wave `wid` merges head `wid` across the 4 wave-slices
  float mstar = -1e30f;
#pragma unroll
  for (int sl = 0; sl < 4; ++sl) mstar = fmaxf(mstar, sm[sl][wid][0]);
  float den = 0.f;
  const int d2 = lane * 2;
  float nx = 0.f, ny = 0.f;
#pragma unroll
  for (int sl = 0; sl < 4; ++sl) {
    float w = __expf(sm[sl][wid][0] - mstar);
    den += w * sm[sl][wid][1];
    nx += w * sm[sl][wid][4 + d2];
    ny += w * sm[sl][wid][4 + d2 + 1];
  }
  float* pp = part + (((size_t)b * NH + kv * 4 + wid) * NCHUNK + chunk) * PSTRIDE;
  if (lane == 0) { pp[0] = mstar; pp[1] = den; }
  float2 nv = {nx, ny};
  *(float2*)(pp + 4 + d2) = nv;
}

// ---------------- Kernel 4: combine chunk partials ------------------------
__global__ void combine(const float* __restrict__ part, float* __restrict__ ctx) {
  const int bh = blockIdx.x;        // 0..511
  const int lane = threadIdx.x;     // 64
  const float* pp = part + (size_t)bh * NCHUNK * PSTRIDE;
  float mstar = -1e30f;
#pragma unroll
  for (int c = 0; c < NCHUNK; ++c) mstar = fmaxf(mstar, pp[c * PSTRIDE]);
  float den = 0.f, nx = 0.f, ny = 0.f;
  const int d2 = lane * 2;
#pragma unroll
  for (int c = 0; c < NCHUNK; ++c) {
    float w = __expf(pp[c * PSTRIDE] - mstar);
    den += w * pp[c * PSTRIDE + 1];
    float2 pv = *(const float2*)(pp + c * PSTRIDE + 4 + d2);
    nx += w * pv.x;
    ny += w * pv.y;
  }
  float inv = 1.0f / den;
  ctx[(size_t)bh * HD + d2] = nx * inv;
  ctx[(size_t)bh * HD + d2 + 1] = ny * inv;
}

// ---------------- Kernel 5: output projection, double-buffered staging -----
__global__ __launch_bounds__(256) void out_proj(
    const float* __restrict__ ctx, const float* __restrict__ Wo,
    float* __restrict__ out) {
  __shared__ __align__(16) float ld[2][16][256];   // 32 KB
  __shared__ __align__(16) float red[4][32][33];   // 16.9 KB
  const int tid = threadIdx.x, wid = tid >> 6, lane = tid & 63;
  const int e0 = blockIdx.x * 8 + wid * 2;
  const int fo = lane * 4;

  float acc[2][16];
#pragma unroll
  for (int r = 0; r < 2; ++r)
#pragma unroll
    for (int b = 0; b < 16; ++b) acc[r][b] = 0.f;

  v4f st[4];
#pragma unroll
  for (int i = 0; i < 4; ++i)
    st[i] = *(const v4f*)(ctx + (size_t)(i * 4 + wid) * DMODEL + fo);
#pragma unroll
  for (int i = 0; i < 4; ++i)
    *(v4f*)(&ld[0][i * 4 + wid][fo]) = st[i];
  v4f w4[2];
#pragma unroll
  for (int r = 0; r < 2; ++r)
    w4[r] = *(const v4f*)(Wo + (size_t)(e0 + r) * DMODEL + fo);
  __syncthreads();

  for (int c = 0; c < 16; ++c) {
    const int k1 = (c + 1) * 256;
    v4f w4n[2];
    if (c < 15) {
#pragma unroll
      for (int i = 0; i < 4; ++i)
        st[i] = *(const v4f*)(ctx + (size_t)(i * 4 + wid) * DMODEL + k1 + fo);
#pragma unroll
      for (int r = 0; r < 2; ++r)
        w4n[r] = *(const v4f*)(Wo + (size_t)(e0 + r) * DMODEL + k1 + fo);
    }
    const float* lb = &ld[c & 1][0][0];
#pragma unroll
    for (int b = 0; b < 16; ++b) {
      v4f h4 = *(const v4f*)(lb + b * 256 + fo);
#pragma unroll
      for (int r = 0; r < 2; ++r) {
        v4f t = w4[r] * h4;
        acc[r][b] += t[0] + t[1] + t[2] + t[3];
      }
    }
    if (c < 15) {
#pragma unroll
      for (int i = 0; i < 4; ++i)
        *(v4f*)(&ld[(c + 1) & 1][i * 4 + wid][fo]) = st[i];
      w4[0] = w4n[0];
      w4[1] = w4n[1];
    }
    __syncthreads();
  }

#pragma unroll
  for (int r = 0; r < 2; ++r)
#pragma unroll
    for (int b = 0; b < 16; ++b) acc[r][b] += __shfl_xor(acc[r][b], 32);

  if (lane < 32) {
#pragma unroll
    for (int r = 0; r < 2; ++r)
#pragma unroll
      for (int b = 0; b < 16; ++b)
        red[wid][lane][r * 16 + b] = acc[r][b];
  }
  __syncthreads();
  if (lane < 32) {
    float s = 0.f;
#pragma unroll
    for (int t2 = 0; t2 < 32; ++t2) s += red[wid][t2][lane];
    const int r = lane >> 4, bb = lane & 15;
    out[(size_t)bb * DMODEL + e0 + r] = s;
  }
}

// ---------------------------------------------------------------------------
extern "C" void kernel_launch(void* const* d_in, const int* in_sizes, int n_in,
                              void* d_out, int out_size, void* d_ws, size_t ws_size,
                              hipStream_t stream) {
  const float* hs    = (const float*)d_in[0];
  const float* mask  = (const float*)d_in[1];
  const void*  pos   = d_in[2];
  const float* pastK = (const float*)d_in[3];
  const float* pastV = (const float*)d_in[4];
  const float* Wq    = (const float*)d_in[5];
  const float* Wk    = (const float*)d_in[6];
  const float* Wv    = (const float*)d_in[7];
  const float* Wo    = (const float*)d_in[8];

  float* out  = (float*)d_out;
  float* attn = out;                                        // 16*4096
  float* kc   = out + (size_t)NB * DMODEL;                  // 16*8*4096*128
  float* vc   = kc + (size_t)NB * NKV * SEQ * HD;

  float* ws      = (float*)d_ws;
  float* ws_q    = ws;                                         // 65536
  float* ws_raw  = ws_q + (size_t)NB * NH * HD;                // 16*6144
  float* ws_part = ws_raw + (size_t)NB * EQKV;                 // 16*32*16*136
  float* ws_ctx  = ws_part + (size_t)NB * NH * NCHUNK * PSTRIDE; // 65536

  qkv_proj<<<EQKV / 8, 256, 0, stream>>>(hs, Wq, Wk, Wv, ws_raw);
  rope_scatter<<<dim3(48, NB), 128, 0, stream>>>(ws_raw, pos, ws_q, kc, vc);
  attn_decode<<<dim3(NCHUNK, NKV, NB), 256, 0, stream>>>(pastK, pastV, ws_q, mask,
                                                         kc, vc, ws_part);
  combine<<<NB * NH, 64, 0, stream>>>(ws_part, ws_ctx);
  out_proj<<<DMODEL / 8, 256, 0, stream>>>(ws_ctx, Wo, attn);
}

// Round 15
// 253.740 us; speedup vs baseline: 1.0325x; 1.0325x over previous
//
#include <hip/hip_runtime.h>

#define NB 16
#define DMODEL 4096
#define NH 32
#define NKV 8
#define HD 128
#define SEQ 4096
#define PASTN 4095
#define EQKV 6144           // 4096 q + 1024 k + 1024 v rows
#define NCHUNK 16
#define CHUNKS 256          // rows per chunk-block (SEQ/NCHUNK)
#define PSTRIDE 136         // partials stride (16B aligned)
#define SCALE 0.08838834764831845f  // 1/sqrt(128)

typedef float v4f __attribute__((ext_vector_type(4)));

// ---------------- Kernel 1: QKV projection, double-buffered staging --------
__global__ __launch_bounds__(256) void qkv_proj(
    const float* __restrict__ hs, const float* __restrict__ Wq,
    const float* __restrict__ Wk, const float* __restrict__ Wv,
    float* __restrict__ raw /* [B][6144] */) {
  __shared__ __align__(16) float ld[2][16][256];   // 32 KB
  __shared__ __align__(16) float red[4][32][33];   // 16.9 KB
  const int tid = threadIdx.x, wid = tid >> 6, lane = tid & 63;
  const int e0 = blockIdx.x * 8 + wid * 2;
  const int fo = lane * 4;

  const float* wrow[2];
#pragma unroll
  for (int r = 0; r < 2; ++r) {
    int e = e0 + r;
    wrow[r] = (e < 4096) ? (Wq + (size_t)e * DMODEL)
            : (e < 5120) ? (Wk + (size_t)(e - 4096) * DMODEL)
                         : (Wv + (size_t)(e - 5120) * DMODEL);
  }

  float acc[2][16];
#pragma unroll
  for (int r = 0; r < 2; ++r)
#pragma unroll
    for (int b = 0; b < 16; ++b) acc[r][b] = 0.f;

  v4f st[4];
#pragma unroll
  for (int i = 0; i < 4; ++i)
    st[i] = *(const v4f*)(hs + (size_t)(i * 4 + wid) * DMODEL + fo);
#pragma unroll
  for (int i = 0; i < 4; ++i)
    *(v4f*)(&ld[0][i * 4 + wid][fo]) = st[i];
  v4f w4[2];
#pragma unroll
  for (int r = 0; r < 2; ++r) w4[r] = *(const v4f*)(wrow[r] + fo);
  __syncthreads();

  for (int c = 0; c < 16; ++c) {
    const int k1 = (c + 1) * 256;
    v4f w4n[2];
    if (c < 15) {
#pragma unroll
      for (int i = 0; i < 4; ++i)
        st[i] = *(const v4f*)(hs + (size_t)(i * 4 + wid) * DMODEL + k1 + fo);
#pragma unroll
      for (int r = 0; r < 2; ++r) w4n[r] = *(const v4f*)(wrow[r] + k1 + fo);
    }
    const float* lb = &ld[c & 1][0][0];
#pragma unroll
    for (int b = 0; b < 16; ++b) {
      v4f h4 = *(const v4f*)(lb + b * 256 + fo);
#pragma unroll
      for (int r = 0; r < 2; ++r) {
        v4f t = w4[r] * h4;
        acc[r][b] += t[0] + t[1] + t[2] + t[3];
      }
    }
    if (c < 15) {
#pragma unroll
      for (int i = 0; i < 4; ++i)
        *(v4f*)(&ld[(c + 1) & 1][i * 4 + wid][fo]) = st[i];
      w4[0] = w4n[0];
      w4[1] = w4n[1];
    }
    __syncthreads();
  }

#pragma unroll
  for (int r = 0; r < 2; ++r)
#pragma unroll
    for (int b = 0; b < 16; ++b) acc[r][b] += __shfl_xor(acc[r][b], 32);

  if (lane < 32) {
#pragma unroll
    for (int r = 0; r < 2; ++r)
#pragma unroll
      for (int b = 0; b < 16; ++b)
        red[wid][lane][r * 16 + b] = acc[r][b];
  }
  __syncthreads();
  if (lane < 32) {
    float s = 0.f;
#pragma unroll
    for (int t2 = 0; t2 < 32; ++t2) s += red[wid][t2][lane];
    const int r = lane >> 4, bb = lane & 15;
    raw[(size_t)bb * EQKV + e0 + r] = s;
  }
}

// ---------------- Kernel 2: RoPE + scatter --------------------------------
__device__ __forceinline__ float rope_val(const float* src, int d, float pos) {
  int i = d & 63;
  float inv_freq = powf(10000.f, -(float)(2 * i) * (1.f / 128.f));
  float ang = pos * inv_freq;
  float s, c;
  sincosf(ang, &s, &c);
  float x = src[d];
  float rot = (d < 64) ? -src[d + 64] : src[d - 64];
  return x * c + rot * s;
}

__global__ void rope_scatter(const float* __restrict__ raw,
                             const void* __restrict__ pos_ids,
                             float* __restrict__ qout,
                             float* __restrict__ kc, float* __restrict__ vc) {
  const int b = blockIdx.y, j = blockIdx.x, d = threadIdx.x;  // 128 threads
  const int* pi = (const int*)pos_ids;
  long long pos = (pi[1] == 0 && pi[0] != 0) ? ((const long long*)pos_ids)[b]
                                             : (long long)pi[b];
  const float fpos = (float)pos;
  if (j < 32) {
    const float* src = raw + (size_t)b * EQKV + j * HD;
    qout[(size_t)b * (NH * HD) + j * HD + d] = rope_val(src, d, fpos);
  } else if (j < 40) {
    int kvh = j - 32;
    const float* src = raw + (size_t)b * EQKV + 4096 + kvh * HD;
    kc[(((size_t)b * NKV + kvh) * SEQ + PASTN) * HD + d] = rope_val(src, d, fpos);
  } else {
    int kvh = j - 40;
    vc[(((size_t)b * NKV + kvh) * SEQ + PASTN) * HD + d] =
        raw[(size_t)b * EQKV + 5120 + kvh * HD + d];
  }
}

// ---------------- Kernel 3: phase-split copy-shaped flash-decode -----------
// grid (16,8,16) = 2048 blocks; 4 waves/block; wave owns 64 rows.
// Phase 1: K-stream only (load + NT write-through + scores, kept in regs).
// Phase 2: true-max per head, then V-stream only (load + write-through +
// exp/accumulate). Each phase = clean 1-read+1-write stream pattern.
__global__ __launch_bounds__(256, 4) void attn_decode(
    const float* __restrict__ pastK, const float* __restrict__ pastV,
    const float* __restrict__ qv, const float* __restrict__ mask,
    float* __restrict__ kc, float* __restrict__ vc,
    float* __restrict__ part /* [B][32][NCHUNK][PSTRIDE] */) {
  __shared__ __align__(16) float sm[4][4][132];  // [wave][head][m,l,pad,ctx128]

  const int chunk = blockIdx.x, kv = blockIdx.y, b = blockIdx.z;
  const int tid = threadIdx.x, wid = tid >> 6, lane = tid & 63;
  const int half = lane >> 5, q32 = lane & 31;
  const int fo = q32 * 4;          // float offset within the lane's row

  v4f q[4];
  const float* qb = qv + (size_t)b * (NH * HD) + kv * 4 * HD + fo;
#pragma unroll
  for (int h = 0; h < 4; ++h) q[h] = *(const v4f*)(qb + h * HD);

  const size_t prow = ((size_t)b * NKV + kv) * PASTN;
  const size_t crow = ((size_t)b * NKV + kv) * SEQ;
  const int base = chunk * CHUNKS + wid * (CHUNKS / 4);
  const float* mrow = mask + (size_t)b * SEQ;

  // mask preload: lane L holds mask[base + 2*(L&31) + (L>>5)];
  // step t's value for this lane sits at source lane t | (lane & 32).
  const float mreg = mrow[base + 2 * q32 + half];

  // keep[h]: score of row (2*q32 + half) for head h (filled in phase 1)
  float keep[4];

  // =================== Phase 1: K stream + scores ===================
  {
    v4f kq[4];
#pragma unroll
    for (int i = 0; i < 4; ++i) {
      const int s = base + 2 * i + half;
      const float* kp = (s < PASTN) ? pastK + (prow + s) * HD + fo
                                    : kc + (crow + s) * HD + fo;
      kq[i] = __builtin_nontemporal_load((const v4f*)kp);
    }

#pragma unroll 4
    for (int t = 0; t < 32; ++t) {
      const int sp = base + 2 * t;
      const int s = sp + half;
      const v4f kch = kq[t & 3];
      if (t < 28) {
        const int s2 = sp + 8 + half;
        const float* kp = (s2 < PASTN) ? pastK + (prow + s2) * HD + fo
                                       : kc + (crow + s2) * HD + fo;
        kq[t & 3] = __builtin_nontemporal_load((const v4f*)kp);
      }
      if (s < PASTN)
        __builtin_nontemporal_store(kch, (v4f*)(kc + (crow + s) * HD + fo));

      const float mval = __shfl(mreg, t | (lane & 32));

      float d4[4];
#pragma unroll
      for (int h = 0; h < 4; ++h) {
        v4f tv = q[h] * kch;
        d4[h] = tv[0] + tv[1] + tv[2] + tv[3];
      }
#pragma unroll
      for (int off = 1; off <= 16; off <<= 1)
#pragma unroll
        for (int h = 0; h < 4; ++h) d4[h] += __shfl_xor(d4[h], off);

#pragma unroll
      for (int h = 0; h < 4; ++h) {
        float sc = d4[h] * SCALE + mval;
        if (q32 == t) keep[h] = sc;   // row 2t+half kept by lane t|(half<<5)
      }
    }
  }

  // =================== Phase 2: true max, V stream ===================
  float m[4], l[4];
  v4f c[4];
#pragma unroll
  for (int h = 0; h < 4; ++h) {
    float mm = keep[h];
#pragma unroll
    for (int off = 1; off <= 32; off <<= 1)
      mm = fmaxf(mm, __shfl_xor(mm, off));
    m[h] = mm;                        // true max over all 64 rows
    l[h] = 0.f;
    c[h] = (v4f){0.f, 0.f, 0.f, 0.f};
  }

  {
    v4f vq[4];
#pragma unroll
    for (int i = 0; i < 4; ++i) {
      const int s = base + 2 * i + half;
      const float* vp = (s < PASTN) ? pastV + (prow + s) * HD + fo
                                    : vc + (crow + s) * HD + fo;
      vq[i] = __builtin_nontemporal_load((const v4f*)vp);
    }

#pragma unroll 4
    for (int t = 0; t < 32; ++t) {
      const int sp = base + 2 * t;
      const int s = sp + half;
      const v4f vch = vq[t & 3];
      if (t < 28) {
        const int s2 = sp + 8 + half;
        const float* vp = (s2 < PASTN) ? pastV + (prow + s2) * HD + fo
                                       : vc + (crow + s2) * HD + fo;
        vq[t & 3] = __builtin_nontemporal_load((const v4f*)vp);
      }
      if (s < PASTN)
        __builtin_nontemporal_store(vch, (v4f*)(vc + (crow + s) * HD + fo));

#pragma unroll
      for (int h = 0; h < 4; ++h) {
        float p = __expf(__shfl(keep[h], t | (lane & 32)) - m[h]);
        l[h] += p;
        c[h] += p * vch;
      }
    }
  }

  // merge the two half-streams (same m — plain add, no rescale)
#pragma unroll
  for (int h = 0; h < 4; ++h) {
    l[h] += __shfl_xor(l[h], 32);
#pragma unroll
    for (int j = 0; j < 4; ++j) c[h][j] += __shfl_xor(c[h][j], 32);
  }

  if (half == 0) {
#pragma unroll
    for (int h = 0; h < 4; ++h) {
      if (q32 == 0) { sm[wid][h][0] = m[h]; sm[wid][h][1] = l[h]; }
      *(v4f*)(&sm[wid][h][4 + fo]) = c[h];
    }
  }
  __syncthreads();

  // wave `wid` merges head `wid` across the 4 wave-slices
  float mstar = -1e30f;
#pragma unroll
  for (int sl = 0; sl < 4; ++sl) mstar = fmaxf(mstar, sm[sl][wid][0]);
  float den = 0.f;
  const int d2 = lane * 2;
  float nx = 0.f, ny = 0.f;
#pragma unroll
  for (int sl = 0; sl < 4; ++sl) {
    float w = __expf(sm[sl][wid][0] - mstar);
    den += w * sm[sl][wid][1];
    nx += w * sm[sl][wid][4 + d2];
    ny += w * sm[sl][wid][4 + d2 + 1];
  }
  float* pp = part + (((size_t)b * NH + kv * 4 + wid) * NCHUNK + chunk) * PSTRIDE;
  if (lane == 0) { pp[0] = mstar; pp[1] = den; }
  float2 nv = {nx, ny};
  *(float2*)(pp + 4 + d2) = nv;
}

// ---------------- Kernel 4: combine chunk partials ------------------------
__global__ void combine(const float* __restrict__ part, float* __restrict__ ctx) {
  const int bh = blockIdx.x;        // 0..511
  const int lane = threadIdx.x;     // 64
  const float* pp = part + (size_t)bh * NCHUNK * PSTRIDE;
  float mstar = -1e30f;
#pragma unroll
  for (int c = 0; c < NCHUNK; ++c) mstar = fmaxf(mstar, pp[c * PSTRIDE]);
  float den = 0.f, nx = 0.f, ny = 0.f;
  const int d2 = lane * 2;
#pragma unroll
  for (int c = 0; c < NCHUNK; ++c) {
    float w = __expf(pp[c * PSTRIDE] - mstar);
    den += w * pp[c * PSTRIDE + 1];
    float2 pv = *(const float2*)(pp + c * PSTRIDE + 4 + d2);
    nx += w * pv.x;
    ny += w * pv.y;
  }
  float inv = 1.0f / den;
  ctx[(size_t)bh * HD + d2] = nx * inv;
  ctx[(size_t)bh * HD + d2 + 1] = ny * inv;
}

// ---------------- Kernel 5: output projection, double-buffered staging -----
__global__ __launch_bounds__(256) void out_proj(
    const float* __restrict__ ctx, const float* __restrict__ Wo,
    float* __restrict__ out) {
  __shared__ __align__(16) float ld[2][16][256];   // 32 KB
  __shared__ __align__(16) float red[4][32][33];   // 16.9 KB
  const int tid = threadIdx.x, wid = tid >> 6, lane = tid & 63;
  const int e0 = blockIdx.x * 8 + wid * 2;
  const int fo = lane * 4;

  float acc[2][16];
#pragma unroll
  for (int r = 0; r < 2; ++r)
#pragma unroll
    for (int b = 0; b < 16; ++b) acc[r][b] = 0.f;

  v4f st[4];
#pragma unroll
  for (int i = 0; i < 4; ++i)
    st[i] = *(const v4f*)(ctx + (size_t)(i * 4 + wid) * DMODEL + fo);
#pragma unroll
  for (int i = 0; i < 4; ++i)
    *(v4f*)(&ld[0][i * 4 + wid][fo]) = st[i];
  v4f w4[2];
#pragma unroll
  for (int r = 0; r < 2; ++r)
    w4[r] = *(const v4f*)(Wo + (size_t)(e0 + r) * DMODEL + fo);
  __syncthreads();

  for (int c = 0; c < 16; ++c) {
    const int k1 = (c + 1) * 256;
    v4f w4n[2];
    if (c < 15) {
#pragma unroll
      for (int i = 0; i < 4; ++i)
        st[i] = *(const v4f*)(ctx + (size_t)(i * 4 + wid) * DMODEL + k1 + fo);
#pragma unroll
      for (int r = 0; r < 2; ++r)
        w4n[r] = *(const v4f*)(Wo + (size_t)(e0 + r) * DMODEL + k1 + fo);
    }
    const float* lb = &ld[c & 1][0][0];
#pragma unroll
    for (int b = 0; b < 16; ++b) {
      v4f h4 = *(const v4f*)(lb + b * 256 + fo);
#pragma unroll
      for (int r = 0; r < 2; ++r) {
        v4f t = w4[r] * h4;
        acc[r][b] += t[0] + t[1] + t[2] + t[3];
      }
    }
    if (c < 15) {
#pragma unroll
      for (int i = 0; i < 4; ++i)
        *(v4f*)(&ld[(c + 1) & 1][i * 4 + wid][fo]) = st[i];
      w4[0] = w4n[0];
      w4[1] = w4n[1];
    }
    __syncthreads();
  }

#pragma unroll
  for (int r = 0; r < 2; ++r)
#pragma unroll
    for (int b = 0; b < 16; ++b) acc[r][b] += __shfl_xor(acc[r][b], 32);

  if (lane < 32) {
#pragma unroll
    for (int r = 0; r < 2; ++r)
#pragma unroll
      for (int b = 0; b < 16; ++b)
        red[wid][lane][r * 16 + b] = acc[r][b];
  }
  __syncthreads();
  if (lane < 32) {
    float s = 0.f;
#pragma unroll
    for (int t2 = 0; t2 < 32; ++t2) s += red[wid][t2][lane];
    const int r = lane >> 4, bb = lane & 15;
    out[(size_t)bb * DMODEL + e0 + r] = s;
  }
}

// ---------------------------------------------------------------------------
extern "C" void kernel_launch(void* const* d_in, const int* in_sizes, int n_in,
                              void* d_out, int out_size, void* d_ws, size_t ws_size,
                              hipStream_t stream) {
  const float* hs    = (const float*)d_in[0];
  const float* mask  = (const float*)d_in[1];
  const void*  pos   = d_in[2];
  const float* pastK = (const float*)d_in[3];
  const float* pastV = (const float*)d_in[4];
  const float* Wq    = (const float*)d_in[5];
  const float* Wk    = (const float*)d_in[6];
  const float* Wv    = (const float*)d_in[7];
  const float* Wo    = (const float*)d_in[8];

  float* out  = (float*)d_out;
  float* attn = out;                                        // 16*4096
  float* kc   = out + (size_t)NB * DMODEL;                  // 16*8*4096*128
  float* vc   = kc + (size_t)NB * NKV * SEQ * HD;

  float* ws      = (float*)d_ws;
  float* ws_q    = ws;                                         // 65536
  float* ws_raw  = ws_q + (size_t)NB * NH * HD;                // 16*6144
  float* ws_part = ws_raw + (size_t)NB * EQKV;                 // 16*32*16*136
  float* ws_ctx  = ws_part + (size_t)NB * NH * NCHUNK * PSTRIDE; // 65536

  qkv_proj<<<EQKV / 8, 256, 0, stream>>>(hs, Wq, Wk, Wv, ws_raw);
  rope_scatter<<<dim3(48, NB), 128, 0, stream>>>(ws_raw, pos, ws_q, kc, vc);
  attn_decode<<<dim3(NCHUNK, NKV, NB), 256, 0, stream>>>(pastK, pastV, ws_q, mask,
                                                         kc, vc, ws_part);
  combine<<<NB * NH, 64, 0, stream>>>(ws_part, ws_ctx);
  out_proj<<<DMODEL / 8, 256, 0, stream>>>(ws_ctx, Wo, attn);
}